// Round 15
// baseline (233.077 us; speedup 1.0000x reference)
//
#include <hip/hip_runtime.h>
#include <cmath>

#define H 8
#define SEQ 2048
#define EDIM 512
#define HD 64
#define EPSF 1e-15f

typedef short bf16x8 __attribute__((ext_vector_type(8)));
typedef float f32x4 __attribute__((ext_vector_type(4)));

// workspace layout (float offsets; 16B-aligned)
#define ZN_OFF    16                                // 3*EDIM; memset covers ZN..ACC
#define ACC_OFF   (ZN_OFF + 3 * EDIM)               // H*SEQ*80 fp32 num/den accumulators
#define STATS_OFF (ACC_OFF + H * SEQ * 80)          // 3*H*SEQ fp32 (rounded q2/k2/v2)
#define CQ_OFF    (STATS_OFF + 3 * H * SEQ)         // H*SEQ: 2/(1-q2)
#define IK_OFF    (CQ_OFF + H * SEQ)                // H*SEQ: 1/(1-k2)
#define U16_OFF   (IK_OFF + H * SEQ + 16)
#define WT_U16    0
#define QKVB_U16  (WT_U16 + 3 * EDIM * EDIM)
#define VT_U16    (QKVB_U16 + 3 * SEQ * EDIM)

__device__ __forceinline__ float bf2f(unsigned short u){
  union { unsigned int i; float f; } v; v.i = ((unsigned int)u) << 16; return v.f;
}
__device__ __forceinline__ unsigned short f2bf(float f){
  union { float f; unsigned int i; } v; v.f = f;
  unsigned int x = v.i;
  unsigned int r = (x + 0x7fffu + ((x >> 16) & 1u)) >> 16;
  return (unsigned short)r;
}

// inline dtype detect: bf16-interpret first 256 u16 of query; fp32 data decodes
// to huge magnitudes w.p. ~1. Butterfly max -> wave-uniform result, no dispatch.
__device__ __forceinline__ int detect_f32(const unsigned short* __restrict__ q){
  const int l = threadIdx.x & 63;
  float mx = 0.f;
  #pragma unroll
  for (int j = 0; j < 4; ++j) mx = fmaxf(mx, fabsf(bf2f(q[l * 4 + j])));
  #pragma unroll
  for (int m = 32; m >= 1; m >>= 1) mx = fmaxf(mx, __shfl_xor(mx, m, 64));
  return mx > 1000.f;
}

// P1: W -> WT bf16 [p][o][i] (transpose) + fp32 column sumsq into zn (pre-zeroed).
__global__ __launch_bounds__(256) void wcvt_kernel(
    const void* __restrict__ Wq, const void* __restrict__ Wk, const void* __restrict__ Wv,
    const unsigned short* __restrict__ qprobe,
    unsigned short* __restrict__ WT, float* __restrict__ zn)
{
  const int p = blockIdx.y;
  const int bi = blockIdx.x >> 3, bo = blockIdx.x & 7;
  const void* W = (p == 0) ? Wq : ((p == 1) ? Wk : Wv);
  const int t = threadIdx.x;
  const int isf32 = detect_f32(qprobe);
  __shared__ float tile[64][65];

  #pragma unroll
  for (int j = 0; j < 16; ++j){
    int idx = t + 256 * j;
    int il = idx >> 6, ol = idx & 63;
    float val;
    if (isf32) val = ((const float*)W)[(size_t)(bi * 64 + il) * EDIM + bo * 64 + ol];
    else       val = bf2f(((const unsigned short*)W)[(size_t)(bi * 64 + il) * EDIM + bo * 64 + ol]);
    tile[il][ol] = val;
  }
  __syncthreads();
  if (t < 64){
    float s = 0.f;
    #pragma unroll 8
    for (int i = 0; i < 64; ++i){ float v = tile[i][t]; s += v * v; }
    atomicAdd(&zn[p * EDIM + bo * 64 + t], s);
  }
  #pragma unroll
  for (int j = 0; j < 16; ++j){
    int idx = t + 256 * j;
    int ol = idx >> 6, il = idx & 63;
    WT[((size_t)p * EDIM + bo * 64 + ol) * EDIM + bi * 64 + il] = f2bf(tile[il][ol]);
  }
}

// K1: hyperbolic linear via MFMA. 8 rows/block (A-frag rows 8..15 duplicate,
// discarded) -> 768 blocks = 3/CU for balance. X conversion fused.
__global__ __launch_bounds__(256) void hlinear_kernel(
    const void* __restrict__ Xq, const void* __restrict__ Xk, const void* __restrict__ Xv,
    const unsigned short* __restrict__ WT,
    const void* __restrict__ Bq, const void* __restrict__ Bk, const void* __restrict__ Bv,
    const float* __restrict__ znacc,
    unsigned short* __restrict__ qkvb, float* __restrict__ stats,
    float* __restrict__ cqs, float* __restrict__ iks,
    unsigned short* __restrict__ VT)
{
  const int p = blockIdx.y;
  const void* X  = (p == 0) ? Xq : ((p == 1) ? Xk : Xv);
  const void* Bb = (p == 0) ? Bq : ((p == 1) ? Bk : Bv);
  const int r0 = blockIdx.x * 8;
  const int t  = threadIdx.x;
  const int w = t >> 6, lane = t & 63;
  const int col = lane & 15, quad = lane >> 4;
  const int isf32 = detect_f32((const unsigned short*)Xq);

  __shared__ float smem[8 * EDIM];
  __shared__ float sw2[8];

  const unsigned short* WTb = WT + ((size_t)p * EDIM + w * 128 + col) * EDIM;
  const float* Xf = (const float*)X + (size_t)(r0 + (col & 7)) * EDIM;
  const unsigned short* Xh = (const unsigned short*)X + (size_t)(r0 + (col & 7)) * EDIM;

  f32x4 acc[8];
  #pragma unroll
  for (int nt = 0; nt < 8; ++nt) acc[nt] = (f32x4){0.f, 0.f, 0.f, 0.f};
  float x2part = 0.f;

  for (int ks = 0; ks < 16; ++ks){
    bf16x8 af;
    if (isf32){
      float4 xa = *(const float4*)&Xf[ks * 32 + quad * 8];
      float4 xb = *(const float4*)&Xf[ks * 32 + quad * 8 + 4];
      float xv[8] = {xa.x, xa.y, xa.z, xa.w, xb.x, xb.y, xb.z, xb.w};
      #pragma unroll
      for (int j = 0; j < 8; ++j){ af[j] = (short)f2bf(xv[j]); x2part += xv[j] * xv[j]; }
    } else {
      af = *(const bf16x8*)&Xh[ks * 32 + quad * 8];
      #pragma unroll
      for (int j = 0; j < 8; ++j){ float xv = bf2f((unsigned short)af[j]); x2part += xv * xv; }
    }
    #pragma unroll
    for (int nt = 0; nt < 8; ++nt){
      bf16x8 bf = *(const bf16x8*)&WTb[(size_t)nt * 16 * EDIM + ks * 32 + quad * 8];
      acc[nt] = __builtin_amdgcn_mfma_f32_16x16x32_bf16(af, bf, acc[nt], 0, 0, 0);
    }
  }
  // full row sumsq of row (col&7): reduce across quads (col fixed)
  x2part += __shfl_xor(x2part, 16, 64);
  x2part += __shfl_xor(x2part, 32, 64);

  // transform: only quad<2 lanes hold valid rows m = quad*4+r < 8
  if (quad < 2){
    float lamr[4], lm1[4];
    #pragma unroll
    for (int r = 0; r < 4; ++r){
      float x2r = __shfl(x2part, quad * 4 + r, 64);   // lane (quad*4+r): col<8, its row
      lamr[r] = 2.f / (1.f - x2r);
      lm1[r] = lamr[r] - 1.f;
    }
    #pragma unroll
    for (int nt = 0; nt < 8; ++nt){
      const int n = w * 128 + nt * 16 + col;
      float znv = fmaxf(sqrtf(znacc[p * EDIM + n]), EPSF);
      float rb;
      if (isf32) rb = ((const float*)Bb)[n];
      else       rb = bf2f(((const unsigned short*)Bb)[n]);
      float e2r = __expf(2.f * rb);
      float ie2r = 1.f / e2r;
      float ch = 0.5f * (e2r + ie2r), sh = 0.5f * (e2r - ie2r);
      float izn = 1.f / znv;
      float tz = 2.f * znv;
      #pragma unroll
      for (int r = 0; r < 4; ++r){
        float a = (acc[nt][r] * lamr[r] * izn) * ch - lm1[r] * sh;
        float b = a + sqrtf(a * a + 1.f);
        float tt = __expf(tz * __logf(b));
        smem[(quad * 4 + r) * EDIM + n] = 0.5f * (tt - 1.f / tt);
      }
    }
  }
  __syncthreads();

  // per-row sum of w^2 (32 threads per row)
  {
    int row = t >> 5, l = t & 31;
    float s = 0.f;
    for (int o = l; o < EDIM; o += 32){ float wv = smem[row * EDIM + o]; s += wv * wv; }
    #pragma unroll
    for (int m = 16; m >= 1; m >>= 1) s += __shfl_xor(s, m, 64);
    if (l == 0) sw2[row] = s;
  }
  __syncthreads();

  // normalize, write qkvb bf16 + stats/cq/ik (+ fused VT & pad for p==2)
  const int o0 = 2 * t;
  const int h0 = t >> 5;
  const int d0 = o0 & 63;
  const int l5 = t & 31;
  #pragma unroll
  for (int rr = 0; rr < 8; ++rr){
    float inv = 1.f / (1.f + sqrtf(1.f + sw2[rr]));
    unsigned short b0 = f2bf(smem[rr * EDIM + o0] * inv);
    unsigned short b1 = f2bf(smem[rr * EDIM + o0 + 1] * inv);
    float r0v = bf2f(b0), r1v = bf2f(b1);
    int s = r0 + rr;
    unsigned int* dst = (unsigned int*)&qkvb[(((size_t)p * H + h0) * SEQ + s) * HD + d0];
    *dst = (unsigned int)b0 | ((unsigned int)b1 << 16);
    float ss = r0v * r0v + r1v * r1v;
    #pragma unroll
    for (int m = 16; m >= 1; m >>= 1) ss += __shfl_xor(ss, m, 64);
    if (p == 2){
      float lam = 2.f / (1.f - ss);
      VT[((size_t)h0 * 80 + d0) * SEQ + s]     = f2bf(r0v * lam);
      VT[((size_t)h0 * 80 + d0 + 1) * SEQ + s] = f2bf(r1v * lam);
      if (l5 < 16)   // row 64 = lam-1; rows 65..79 = zero pad
        VT[((size_t)h0 * 80 + 64 + l5) * SEQ + s] = (l5 == 0) ? f2bf(lam - 1.f) : 0;
    }
    if (l5 == 0){
      stats[((size_t)p * H + h0) * SEQ + s] = ss;
      if (p == 0) cqs[(size_t)h0 * SEQ + s] = 2.f / (1.f - ss);
      if (p == 1) iks[(size_t)h0 * SEQ + s] = 1.f / (1.f - ss);
    }
  }
}

// K3a: attention — R11 structure (64-q supertile x 8 k-slices, shuffle
// P-transpose, exp/log weights, atomicAdd epilogue) + EXPLICIT half-chunk
// software pipeline: next 32-key half's K-frags/k2/ik loaded into a register
// double-buffer before computing the current half (load-use distance = one body).
__global__ __launch_bounds__(256) void attn_kernel(
    const unsigned short* __restrict__ Qb, const unsigned short* __restrict__ Kb,
    const unsigned short* __restrict__ VT,
    const float* __restrict__ q2s_all, const float* __restrict__ k2s_all,
    const float* __restrict__ cqs_all, const float* __restrict__ iks_all,
    const void* __restrict__ tau, const void* __restrict__ gam,
    const unsigned short* __restrict__ qprobe,
    float* __restrict__ ACC)
{
  const int h  = blockIdx.y;
  const int tile = blockIdx.x >> 3;      // 64-q supertile 0..31
  const int sl = blockIdx.x & 7;         // k-slice
  if (sl > tile) return;
  const int t = threadIdx.x;
  const int w = t >> 6, lane = t & 63;
  const int col = lane & 15, quad = lane >> 4;
  const int q0 = tile * 64 + w * 16;

  const unsigned short* Qh  = Qb + (size_t)h * SEQ * HD;
  const unsigned short* Kh  = Kb + (size_t)h * SEQ * HD;
  const unsigned short* VTh = VT + (size_t)h * 80 * SEQ;
  const float* q2s = q2s_all + (size_t)h * SEQ;
  const float* k2s = k2s_all + (size_t)h * SEQ;
  const float* cqs = cqs_all + (size_t)h * SEQ;
  const float* iks = iks_all + (size_t)h * SEQ;

  const int isf32 = detect_f32(qprobe);
  float tauv, gamv;
  if (isf32){ tauv = ((const float*)tau)[0]; gamv = ((const float*)gam)[0]; }
  else      { tauv = bf2f(((const unsigned short*)tau)[0]);
              gamv = bf2f(((const unsigned short*)gam)[0]); }
  const float e_tau = __expf(tauv);

  const int srcA = ((quad & 1) * 2) * 16 + col;
  const int srcB = srcA + 16;
  const int tsel = quad >> 1;

  bf16x8 qf0 = *(const bf16x8*)&Qh[(size_t)(q0 + col) * HD + quad * 8];
  bf16x8 qf1 = *(const bf16x8*)&Qh[(size_t)(q0 + col) * HD + 32 + quad * 8];
  const float q2 = q2s[q0 + col];
  const float cq = cqs[q0 + col];
  const int qmax = q0 + col;

  f32x4 pv[5];
  #pragma unroll
  for (int nt = 0; nt < 5; ++nt) pv[nt] = (f32x4){0.f, 0.f, 0.f, 0.f};

  const int nch = ((tile - sl) >> 3) + 1;   // chunks: sl, sl+8, ..., <= tile
  const int nhalf = nch * 2;
  int kb32 = sl * 64;

  bf16x8 ckf0[2], ckf1[2], nkf0[2], nkf1[2];
  float4 ck2[2], cik[2], nk2[2], nik[2];
  #pragma unroll
  for (int tt = 0; tt < 2; ++tt){
    const int kbase = kb32 + 16 * tt;
    ckf0[tt] = *(const bf16x8*)&Kh[(size_t)(kbase + col) * HD + quad * 8];
    ckf1[tt] = *(const bf16x8*)&Kh[(size_t)(kbase + col) * HD + 32 + quad * 8];
    ck2[tt]  = *(const float4*)&k2s[kbase + quad * 4];
    cik[tt]  = *(const float4*)&iks[kbase + quad * 4];
  }

  for (int i = 0; i < nhalf; ++i){
    const int nkb32 = (i & 1) ? (kb32 + 512 - 32) : (kb32 + 32);
    const bool have_next = (i + 1 < nhalf);
    if (have_next){
      #pragma unroll
      for (int tt = 0; tt < 2; ++tt){
        const int kbase = nkb32 + 16 * tt;
        nkf0[tt] = *(const bf16x8*)&Kh[(size_t)(kbase + col) * HD + quad * 8];
        nkf1[tt] = *(const bf16x8*)&Kh[(size_t)(kbase + col) * HD + 32 + quad * 8];
        nk2[tt]  = *(const float4*)&k2s[kbase + quad * 4];
        nik[tt]  = *(const float4*)&iks[kbase + quad * 4];
      }
    }

    // ---- compute current half at kb32 ----
    unsigned int tlo[2], thi[2];
    #pragma unroll
    for (int tt = 0; tt < 2; ++tt){
      const int kbase = kb32 + 16 * tt;
      f32x4 s = (f32x4){0.f, 0.f, 0.f, 0.f};
      s = __builtin_amdgcn_mfma_f32_16x16x32_bf16(ckf0[tt], qf0, s, 0, 0, 0);
      s = __builtin_amdgcn_mfma_f32_16x16x32_bf16(ckf1[tt], qf1, s, 0, 0, 0);
      unsigned short pb[4];
      #pragma unroll
      for (int r = 0; r < 4; ++r){
        float k2 = (r == 0) ? ck2[tt].x : (r == 1) ? ck2[tt].y : (r == 2) ? ck2[tt].z : ck2[tt].w;
        float ik = (r == 0) ? cik[tt].x : (r == 1) ? cik[tt].y : (r == 2) ? cik[tt].z : cik[tt].w;
        float diff2 = fmaxf(q2 + k2 - 2.f * s[r], 0.f);
        float u = fmaxf(diff2 * cq * ik, 1e-7f);
        float z = 1.f + u + sqrtf(u * (u + 2.f));
        float dist = __logf(z);
        float wv = __expf(-e_tau * dist - gamv);
        int key = kbase + quad * 4 + r;
        if (key > qmax) wv = 0.f;
        pb[r] = f2bf(wv);
      }
      tlo[tt] = (unsigned int)pb[0] | ((unsigned int)pb[1] << 16);
      thi[tt] = (unsigned int)pb[2] | ((unsigned int)pb[3] << 16);
    }
    unsigned int a0 = (unsigned int)__shfl((int)tlo[0], srcA, 64);
    unsigned int a1 = (unsigned int)__shfl((int)tlo[1], srcA, 64);
    unsigned int b0 = (unsigned int)__shfl((int)thi[0], srcA, 64);
    unsigned int b1 = (unsigned int)__shfl((int)thi[1], srcA, 64);
    unsigned int c0 = (unsigned int)__shfl((int)tlo[0], srcB, 64);
    unsigned int c1 = (unsigned int)__shfl((int)tlo[1], srcB, 64);
    unsigned int d0 = (unsigned int)__shfl((int)thi[0], srcB, 64);
    unsigned int d1 = (unsigned int)__shfl((int)thi[1], srcB, 64);
    union { uint4 u; bf16x8 v; } pw;
    pw.u.x = tsel ? a1 : a0;
    pw.u.y = tsel ? b1 : b0;
    pw.u.z = tsel ? c1 : c0;
    pw.u.w = tsel ? d1 : d0;
    #pragma unroll
    for (int nt = 0; nt < 5; ++nt){
      bf16x8 vf = *(const bf16x8*)&VTh[(size_t)(16 * nt + col) * SEQ + kb32 + quad * 8];
      pv[nt] = __builtin_amdgcn_mfma_f32_16x16x32_bf16(pw.v, vf, pv[nt], 0, 0, 0);
    }

    // rotate buffers
    if (have_next){
      #pragma unroll
      for (int tt = 0; tt < 2; ++tt){
        ckf0[tt] = nkf0[tt]; ckf1[tt] = nkf1[tt];
        ck2[tt] = nk2[tt];   cik[tt] = nik[tt];
      }
    }
    kb32 = nkb32;
  }

  #pragma unroll
  for (int r = 0; r < 4; ++r){
    float* row = ACC + ((size_t)h * SEQ + q0 + quad * 4 + r) * 80;
    #pragma unroll
    for (int nt = 0; nt < 5; ++nt)
      atomicAdd(&row[16 * nt + col], pv[nt][r]);
  }
}

// K3b: gyromidpoint epilogue from ACC. Grid (128, H), 64 threads.
__global__ __launch_bounds__(64) void attn_fin_kernel(
    const float* __restrict__ ACC, float* __restrict__ out, float beta_scale)
{
  const int h = blockIdx.y, tile = blockIdx.x;
  const int t = threadIdx.x;
  const int col = t & 15, quad = t >> 4;
  const int q0 = tile * 16;

  f32x4 pv[5];
  #pragma unroll
  for (int nt = 0; nt < 5; ++nt)
    #pragma unroll
    for (int r = 0; r < 4; ++r)
      pv[nt][r] = ACC[((size_t)h * SEQ + q0 + quad * 4 + r) * 80 + 16 * nt + col];

  #pragma unroll
  for (int r = 0; r < 4; ++r){
    float den = __shfl(pv[4][r], quad * 16, 64);
    den = fmaxf(den, EPSF);
    float inv_den = 1.f / den;
    float g[4];
    float gsq = 0.f;
    #pragma unroll
    for (int nt = 0; nt < 4; ++nt){ g[nt] = pv[nt][r] * inv_den; gsq += g[nt] * g[nt]; }
    #pragma unroll
    for (int m = 8; m >= 1; m >>= 1) gsq += __shfl_xor(gsq, m, 64);
    float gn = fmaxf(sqrtf(gsq), EPSF);
    float x = fminf(gn, 1.f - 1e-7f);
    float tt2 = x / (1.f + sqrtf(1.f - x * x));
    float scl = (tt2 / gn) * beta_scale;
    const int q = q0 + quad * 4 + r;
    #pragma unroll
    for (int nt = 0; nt < 4; ++nt)
      out[(size_t)q * EDIM + h * HD + 16 * nt + col] = g[nt] * scl;
  }
}

extern "C" void kernel_launch(void* const* d_in, const int* in_sizes, int n_in,
                              void* d_out, int out_size, void* d_ws, size_t ws_size,
                              hipStream_t stream){
  const void* Xq  = d_in[0];
  const void* Xk  = d_in[1];
  const void* Xv  = d_in[2];
  const void* Wq  = d_in[3];
  const void* Wk  = d_in[4];
  const void* Wv  = d_in[5];
  const void* Bq  = d_in[6];
  const void* Bk  = d_in[7];
  const void* Bv  = d_in[8];
  const void* tau = d_in[9];
  const void* gam = d_in[10];

  float* wsf   = (float*)d_ws;
  float* zn    = wsf + ZN_OFF;
  float* ACC   = wsf + ACC_OFF;
  float* stats = wsf + STATS_OFF;
  float* cqs   = wsf + CQ_OFF;
  float* iks   = wsf + IK_OFF;
  unsigned short* u16b = (unsigned short*)(wsf + U16_OFF);
  unsigned short* WT   = u16b + WT_U16;
  unsigned short* qkvb = u16b + QKVB_U16;
  unsigned short* VT   = u16b + VT_U16;

  unsigned short* Qb = qkvb;
  unsigned short* Kb = qkvb + (size_t)H * SEQ * HD;
  float* q2s = stats;
  float* k2s = stats + (size_t)H * SEQ;
  const unsigned short* qprobe = (const unsigned short*)Xq;

  double lb1 = lgamma(EDIM / 2.0) + lgamma(0.5) - lgamma(EDIM / 2.0 + 0.5);
  double lb2 = lgamma(HD / 2.0)   + lgamma(0.5) - lgamma(HD / 2.0 + 0.5);
  float beta_scale = (float)exp(lb1 - lb2);

  hipMemsetAsync(zn, 0, (size_t)(3 * EDIM + H * SEQ * 80) * sizeof(float), stream);
  wcvt_kernel<<<dim3(64, 3), dim3(256), 0, stream>>>(Wq, Wk, Wv, qprobe, WT, zn);
  hlinear_kernel<<<dim3(SEQ / 8, 3), dim3(256), 0, stream>>>(
      Xq, Xk, Xv, WT, Bq, Bk, Bv, zn, qkvb, stats, cqs, iks, VT);
  attn_kernel<<<dim3(32 * 8, H), dim3(256), 0, stream>>>(
      Qb, Kb, VT, q2s, k2s, cqs, iks, tau, gam, qprobe, ACC);
  attn_fin_kernel<<<dim3(128, H), dim3(64), 0, stream>>>(
      ACC, (float*)d_out, beta_scale);
}

// Round 16
// 213.264 us; speedup vs baseline: 1.0929x; 1.0929x over previous
//
#include <hip/hip_runtime.h>
#include <cmath>

#define H 8
#define SEQ 2048
#define EDIM 512
#define HD 64
#define EPSF 1e-15f

typedef short bf16x8 __attribute__((ext_vector_type(8)));
typedef float f32x4 __attribute__((ext_vector_type(4)));

// workspace layout (float offsets; 16B-aligned)
#define ZN_OFF    16                                // 3*EDIM; memset covers ZN..ACC
#define ACC_OFF   (ZN_OFF + 3 * EDIM)               // H*SEQ*80 fp32 num/den accumulators
#define STATS_OFF (ACC_OFF + H * SEQ * 80)          // 3*H*SEQ fp32 (rounded q2/k2/v2)
#define CQ_OFF    (STATS_OFF + 3 * H * SEQ)         // H*SEQ: 2/(1-q2)
#define IK_OFF    (CQ_OFF + H * SEQ)                // H*SEQ: 1/(1-k2)
#define U16_OFF   (IK_OFF + H * SEQ + 16)
#define WT_U16    0
#define QKVB_U16  (WT_U16 + 3 * EDIM * EDIM)
#define VT_U16    (QKVB_U16 + 3 * SEQ * EDIM)

__device__ __forceinline__ float bf2f(unsigned short u){
  union { unsigned int i; float f; } v; v.i = ((unsigned int)u) << 16; return v.f;
}
__device__ __forceinline__ unsigned short f2bf(float f){
  union { float f; unsigned int i; } v; v.f = f;
  unsigned int x = v.i;
  unsigned int r = (x + 0x7fffu + ((x >> 16) & 1u)) >> 16;
  return (unsigned short)r;
}

// inline dtype detect: bf16-interpret first 256 u16 of query; fp32 data decodes
// to huge magnitudes w.p. ~1. Butterfly max -> wave-uniform result, no dispatch.
__device__ __forceinline__ int detect_f32(const unsigned short* __restrict__ q){
  const int l = threadIdx.x & 63;
  float mx = 0.f;
  #pragma unroll
  for (int j = 0; j < 4; ++j) mx = fmaxf(mx, fabsf(bf2f(q[l * 4 + j])));
  #pragma unroll
  for (int m = 32; m >= 1; m >>= 1) mx = fmaxf(mx, __shfl_xor(mx, m, 64));
  return mx > 1000.f;
}

// P1: W -> WT bf16 [p][o][i] (transpose) + fp32 column sumsq into zn (pre-zeroed).
__global__ __launch_bounds__(256) void wcvt_kernel(
    const void* __restrict__ Wq, const void* __restrict__ Wk, const void* __restrict__ Wv,
    const unsigned short* __restrict__ qprobe,
    unsigned short* __restrict__ WT, float* __restrict__ zn)
{
  const int p = blockIdx.y;
  const int bi = blockIdx.x >> 3, bo = blockIdx.x & 7;
  const void* W = (p == 0) ? Wq : ((p == 1) ? Wk : Wv);
  const int t = threadIdx.x;
  const int isf32 = detect_f32(qprobe);
  __shared__ float tile[64][65];

  #pragma unroll
  for (int j = 0; j < 16; ++j){
    int idx = t + 256 * j;
    int il = idx >> 6, ol = idx & 63;
    float val;
    if (isf32) val = ((const float*)W)[(size_t)(bi * 64 + il) * EDIM + bo * 64 + ol];
    else       val = bf2f(((const unsigned short*)W)[(size_t)(bi * 64 + il) * EDIM + bo * 64 + ol]);
    tile[il][ol] = val;
  }
  __syncthreads();
  if (t < 64){
    float s = 0.f;
    #pragma unroll 8
    for (int i = 0; i < 64; ++i){ float v = tile[i][t]; s += v * v; }
    atomicAdd(&zn[p * EDIM + bo * 64 + t], s);
  }
  #pragma unroll
  for (int j = 0; j < 16; ++j){
    int idx = t + 256 * j;
    int ol = idx >> 6, il = idx & 63;
    WT[((size_t)p * EDIM + bo * 64 + ol) * EDIM + bi * 64 + il] = f2bf(tile[il][ol]);
  }
}

// K1: hyperbolic linear via MFMA, 16 rows/block, X conversion fused.
// (Exact R13/R14 structure — measured <=79us in the 217.9 total config.)
__global__ __launch_bounds__(256) void hlinear_kernel(
    const void* __restrict__ Xq, const void* __restrict__ Xk, const void* __restrict__ Xv,
    const unsigned short* __restrict__ WT,
    const void* __restrict__ Bq, const void* __restrict__ Bk, const void* __restrict__ Bv,
    const float* __restrict__ znacc,
    unsigned short* __restrict__ qkvb, float* __restrict__ stats,
    float* __restrict__ cqs, float* __restrict__ iks,
    unsigned short* __restrict__ VT)
{
  const int p = blockIdx.y;
  const void* X  = (p == 0) ? Xq : ((p == 1) ? Xk : Xv);
  const void* Bb = (p == 0) ? Bq : ((p == 1) ? Bk : Bv);
  const int r0 = blockIdx.x * 16;
  const int t  = threadIdx.x;
  const int w = t >> 6, lane = t & 63;
  const int col = lane & 15, quad = lane >> 4;
  const int isf32 = detect_f32((const unsigned short*)Xq);

  __shared__ float smem[16 * EDIM];
  __shared__ float sw2[16];

  const unsigned short* WTb = WT + ((size_t)p * EDIM + w * 128 + col) * EDIM;
  const float* Xf = (const float*)X + (size_t)(r0 + col) * EDIM;
  const unsigned short* Xh = (const unsigned short*)X + (size_t)(r0 + col) * EDIM;

  f32x4 acc[8];
  #pragma unroll
  for (int nt = 0; nt < 8; ++nt) acc[nt] = (f32x4){0.f, 0.f, 0.f, 0.f};
  float x2part = 0.f;

  for (int ks = 0; ks < 16; ++ks){
    bf16x8 af;
    if (isf32){
      float4 xa = *(const float4*)&Xf[ks * 32 + quad * 8];
      float4 xb = *(const float4*)&Xf[ks * 32 + quad * 8 + 4];
      float xv[8] = {xa.x, xa.y, xa.z, xa.w, xb.x, xb.y, xb.z, xb.w};
      #pragma unroll
      for (int j = 0; j < 8; ++j){ af[j] = (short)f2bf(xv[j]); x2part += xv[j] * xv[j]; }
    } else {
      af = *(const bf16x8*)&Xh[ks * 32 + quad * 8];
      #pragma unroll
      for (int j = 0; j < 8; ++j){ float xv = bf2f((unsigned short)af[j]); x2part += xv * xv; }
    }
    #pragma unroll
    for (int nt = 0; nt < 8; ++nt){
      bf16x8 bf = *(const bf16x8*)&WTb[(size_t)nt * 16 * EDIM + ks * 32 + quad * 8];
      acc[nt] = __builtin_amdgcn_mfma_f32_16x16x32_bf16(af, bf, acc[nt], 0, 0, 0);
    }
  }
  x2part += __shfl_xor(x2part, 16, 64);
  x2part += __shfl_xor(x2part, 32, 64);
  float lamr[4], lm1[4];
  #pragma unroll
  for (int r = 0; r < 4; ++r){
    float x2r = __shfl(x2part, quad * 4 + r, 64);
    lamr[r] = 2.f / (1.f - x2r);
    lm1[r] = lamr[r] - 1.f;
  }
  #pragma unroll
  for (int nt = 0; nt < 8; ++nt){
    const int n = w * 128 + nt * 16 + col;
    float znv = fmaxf(sqrtf(znacc[p * EDIM + n]), EPSF);
    float rb;
    if (isf32) rb = ((const float*)Bb)[n];
    else       rb = bf2f(((const unsigned short*)Bb)[n]);
    float e2r = __expf(2.f * rb);
    float ie2r = 1.f / e2r;
    float ch = 0.5f * (e2r + ie2r), sh = 0.5f * (e2r - ie2r);
    float izn = 1.f / znv;
    float tz = 2.f * znv;
    #pragma unroll
    for (int r = 0; r < 4; ++r){
      float a = (acc[nt][r] * lamr[r] * izn) * ch - lm1[r] * sh;
      float b = a + sqrtf(a * a + 1.f);
      float tt = __expf(tz * __logf(b));
      smem[(quad * 4 + r) * EDIM + n] = 0.5f * (tt - 1.f / tt);
    }
  }
  __syncthreads();

  {
    int row = t >> 4, l = t & 15;
    float s = 0.f;
    for (int o = l; o < EDIM; o += 16){ float wv = smem[row * EDIM + o]; s += wv * wv; }
    #pragma unroll
    for (int m = 8; m >= 1; m >>= 1) s += __shfl_xor(s, m, 16);
    if (l == 0) sw2[row] = s;
  }
  __syncthreads();

  const int o0 = 2 * t;
  const int h0 = t >> 5;
  const int d0 = o0 & 63;
  const int l5 = t & 31;
  #pragma unroll
  for (int rr = 0; rr < 16; ++rr){
    float inv = 1.f / (1.f + sqrtf(1.f + sw2[rr]));
    unsigned short b0 = f2bf(smem[rr * EDIM + o0] * inv);
    unsigned short b1 = f2bf(smem[rr * EDIM + o0 + 1] * inv);
    float r0v = bf2f(b0), r1v = bf2f(b1);
    int s = r0 + rr;
    unsigned int* dst = (unsigned int*)&qkvb[(((size_t)p * H + h0) * SEQ + s) * HD + d0];
    *dst = (unsigned int)b0 | ((unsigned int)b1 << 16);
    float ss = r0v * r0v + r1v * r1v;
    #pragma unroll
    for (int m = 16; m >= 1; m >>= 1) ss += __shfl_xor(ss, m, 64);
    if (p == 2){
      float lam = 2.f / (1.f - ss);
      VT[((size_t)h0 * 80 + d0) * SEQ + s]     = f2bf(r0v * lam);
      VT[((size_t)h0 * 80 + d0 + 1) * SEQ + s] = f2bf(r1v * lam);
      if (l5 < 16)
        VT[((size_t)h0 * 80 + 64 + l5) * SEQ + s] = (l5 == 0) ? f2bf(lam - 1.f) : 0;
    }
    if (l5 == 0){
      stats[((size_t)p * H + h0) * SEQ + s] = ss;
      if (p == 0) cqs[(size_t)h0 * SEQ + s] = 2.f / (1.f - ss);
      if (p == 1) iks[(size_t)h0 * SEQ + s] = 1.f / (1.f - ss);
    }
  }
}

// K3a: attention — R11 structure (64-q supertile x 8 k-slices, shuffle
// P-transpose, exp/log weights, atomicAdd epilogue) + EXPLICIT half-chunk
// software pipeline (R15): next 32-key half's K-frags/k2/ik loaded into a
// register double-buffer before computing the current half.
__global__ __launch_bounds__(256) void attn_kernel(
    const unsigned short* __restrict__ Qb, const unsigned short* __restrict__ Kb,
    const unsigned short* __restrict__ VT,
    const float* __restrict__ q2s_all, const float* __restrict__ k2s_all,
    const float* __restrict__ cqs_all, const float* __restrict__ iks_all,
    const void* __restrict__ tau, const void* __restrict__ gam,
    const unsigned short* __restrict__ qprobe,
    float* __restrict__ ACC)
{
  const int h  = blockIdx.y;
  const int tile = blockIdx.x >> 3;      // 64-q supertile 0..31
  const int sl = blockIdx.x & 7;         // k-slice
  if (sl > tile) return;
  const int t = threadIdx.x;
  const int w = t >> 6, lane = t & 63;
  const int col = lane & 15, quad = lane >> 4;
  const int q0 = tile * 64 + w * 16;

  const unsigned short* Qh  = Qb + (size_t)h * SEQ * HD;
  const unsigned short* Kh  = Kb + (size_t)h * SEQ * HD;
  const unsigned short* VTh = VT + (size_t)h * 80 * SEQ;
  const float* q2s = q2s_all + (size_t)h * SEQ;
  const float* k2s = k2s_all + (size_t)h * SEQ;
  const float* cqs = cqs_all + (size_t)h * SEQ;
  const float* iks = iks_all + (size_t)h * SEQ;

  const int isf32 = detect_f32(qprobe);
  float tauv, gamv;
  if (isf32){ tauv = ((const float*)tau)[0]; gamv = ((const float*)gam)[0]; }
  else      { tauv = bf2f(((const unsigned short*)tau)[0]);
              gamv = bf2f(((const unsigned short*)gam)[0]); }
  const float e_tau = __expf(tauv);

  const int srcA = ((quad & 1) * 2) * 16 + col;
  const int srcB = srcA + 16;
  const int tsel = quad >> 1;

  bf16x8 qf0 = *(const bf16x8*)&Qh[(size_t)(q0 + col) * HD + quad * 8];
  bf16x8 qf1 = *(const bf16x8*)&Qh[(size_t)(q0 + col) * HD + 32 + quad * 8];
  const float q2 = q2s[q0 + col];
  const float cq = cqs[q0 + col];
  const int qmax = q0 + col;

  f32x4 pv[5];
  #pragma unroll
  for (int nt = 0; nt < 5; ++nt) pv[nt] = (f32x4){0.f, 0.f, 0.f, 0.f};

  const int nch = ((tile - sl) >> 3) + 1;   // chunks: sl, sl+8, ..., <= tile
  const int nhalf = nch * 2;
  int kb32 = sl * 64;

  bf16x8 ckf0[2], ckf1[2], nkf0[2], nkf1[2];
  float4 ck2[2], cik[2], nk2[2], nik[2];
  #pragma unroll
  for (int tt = 0; tt < 2; ++tt){
    const int kbase = kb32 + 16 * tt;
    ckf0[tt] = *(const bf16x8*)&Kh[(size_t)(kbase + col) * HD + quad * 8];
    ckf1[tt] = *(const bf16x8*)&Kh[(size_t)(kbase + col) * HD + 32 + quad * 8];
    ck2[tt]  = *(const float4*)&k2s[kbase + quad * 4];
    cik[tt]  = *(const float4*)&iks[kbase + quad * 4];
  }

  for (int i = 0; i < nhalf; ++i){
    const int nkb32 = (i & 1) ? (kb32 + 512 - 32) : (kb32 + 32);
    const bool have_next = (i + 1 < nhalf);
    if (have_next){
      #pragma unroll
      for (int tt = 0; tt < 2; ++tt){
        const int kbase = nkb32 + 16 * tt;
        nkf0[tt] = *(const bf16x8*)&Kh[(size_t)(kbase + col) * HD + quad * 8];
        nkf1[tt] = *(const bf16x8*)&Kh[(size_t)(kbase + col) * HD + 32 + quad * 8];
        nk2[tt]  = *(const float4*)&k2s[kbase + quad * 4];
        nik[tt]  = *(const float4*)&iks[kbase + quad * 4];
      }
    }

    // ---- compute current half at kb32 ----
    unsigned int tlo[2], thi[2];
    #pragma unroll
    for (int tt = 0; tt < 2; ++tt){
      const int kbase = kb32 + 16 * tt;
      f32x4 s = (f32x4){0.f, 0.f, 0.f, 0.f};
      s = __builtin_amdgcn_mfma_f32_16x16x32_bf16(ckf0[tt], qf0, s, 0, 0, 0);
      s = __builtin_amdgcn_mfma_f32_16x16x32_bf16(ckf1[tt], qf1, s, 0, 0, 0);
      unsigned short pb[4];
      #pragma unroll
      for (int r = 0; r < 4; ++r){
        float k2 = (r == 0) ? ck2[tt].x : (r == 1) ? ck2[tt].y : (r == 2) ? ck2[tt].z : ck2[tt].w;
        float ik = (r == 0) ? cik[tt].x : (r == 1) ? cik[tt].y : (r == 2) ? cik[tt].z : cik[tt].w;
        float diff2 = fmaxf(q2 + k2 - 2.f * s[r], 0.f);
        float u = fmaxf(diff2 * cq * ik, 1e-7f);
        float z = 1.f + u + sqrtf(u * (u + 2.f));
        float dist = __logf(z);
        float wv = __expf(-e_tau * dist - gamv);
        int key = kbase + quad * 4 + r;
        if (key > qmax) wv = 0.f;
        pb[r] = f2bf(wv);
      }
      tlo[tt] = (unsigned int)pb[0] | ((unsigned int)pb[1] << 16);
      thi[tt] = (unsigned int)pb[2] | ((unsigned int)pb[3] << 16);
    }
    unsigned int a0 = (unsigned int)__shfl((int)tlo[0], srcA, 64);
    unsigned int a1 = (unsigned int)__shfl((int)tlo[1], srcA, 64);
    unsigned int b0 = (unsigned int)__shfl((int)thi[0], srcA, 64);
    unsigned int b1 = (unsigned int)__shfl((int)thi[1], srcA, 64);
    unsigned int c0 = (unsigned int)__shfl((int)tlo[0], srcB, 64);
    unsigned int c1 = (unsigned int)__shfl((int)tlo[1], srcB, 64);
    unsigned int d0 = (unsigned int)__shfl((int)thi[0], srcB, 64);
    unsigned int d1 = (unsigned int)__shfl((int)thi[1], srcB, 64);
    union { uint4 u; bf16x8 v; } pw;
    pw.u.x = tsel ? a1 : a0;
    pw.u.y = tsel ? b1 : b0;
    pw.u.z = tsel ? c1 : c0;
    pw.u.w = tsel ? d1 : d0;
    #pragma unroll
    for (int nt = 0; nt < 5; ++nt){
      bf16x8 vf = *(const bf16x8*)&VTh[(size_t)(16 * nt + col) * SEQ + kb32 + quad * 8];
      pv[nt] = __builtin_amdgcn_mfma_f32_16x16x32_bf16(pw.v, vf, pv[nt], 0, 0, 0);
    }

    // rotate buffers
    if (have_next){
      #pragma unroll
      for (int tt = 0; tt < 2; ++tt){
        ckf0[tt] = nkf0[tt]; ckf1[tt] = nkf1[tt];
        ck2[tt] = nk2[tt];   cik[tt] = nik[tt];
      }
    }
    kb32 = nkb32;
  }

  #pragma unroll
  for (int r = 0; r < 4; ++r){
    float* row = ACC + ((size_t)h * SEQ + q0 + quad * 4 + r) * 80;
    #pragma unroll
    for (int nt = 0; nt < 5; ++nt)
      atomicAdd(&row[16 * nt + col], pv[nt][r]);
  }
}

// K3b: gyromidpoint epilogue from ACC. Grid (128, H), 64 threads.
__global__ __launch_bounds__(64) void attn_fin_kernel(
    const float* __restrict__ ACC, float* __restrict__ out, float beta_scale)
{
  const int h = blockIdx.y, tile = blockIdx.x;
  const int t = threadIdx.x;
  const int col = t & 15, quad = t >> 4;
  const int q0 = tile * 16;

  f32x4 pv[5];
  #pragma unroll
  for (int nt = 0; nt < 5; ++nt)
    #pragma unroll
    for (int r = 0; r < 4; ++r)
      pv[nt][r] = ACC[((size_t)h * SEQ + q0 + quad * 4 + r) * 80 + 16 * nt + col];

  #pragma unroll
  for (int r = 0; r < 4; ++r){
    float den = __shfl(pv[4][r], quad * 16, 64);
    den = fmaxf(den, EPSF);
    float inv_den = 1.f / den;
    float g[4];
    float gsq = 0.f;
    #pragma unroll
    for (int nt = 0; nt < 4; ++nt){ g[nt] = pv[nt][r] * inv_den; gsq += g[nt] * g[nt]; }
    #pragma unroll
    for (int m = 8; m >= 1; m >>= 1) gsq += __shfl_xor(gsq, m, 64);
    float gn = fmaxf(sqrtf(gsq), EPSF);
    float x = fminf(gn, 1.f - 1e-7f);
    float tt2 = x / (1.f + sqrtf(1.f - x * x));
    float scl = (tt2 / gn) * beta_scale;
    const int q = q0 + quad * 4 + r;
    #pragma unroll
    for (int nt = 0; nt < 4; ++nt)
      out[(size_t)q * EDIM + h * HD + 16 * nt + col] = g[nt] * scl;
  }
}

extern "C" void kernel_launch(void* const* d_in, const int* in_sizes, int n_in,
                              void* d_out, int out_size, void* d_ws, size_t ws_size,
                              hipStream_t stream){
  const void* Xq  = d_in[0];
  const void* Xk  = d_in[1];
  const void* Xv  = d_in[2];
  const void* Wq  = d_in[3];
  const void* Wk  = d_in[4];
  const void* Wv  = d_in[5];
  const void* Bq  = d_in[6];
  const void* Bk  = d_in[7];
  const void* Bv  = d_in[8];
  const void* tau = d_in[9];
  const void* gam = d_in[10];

  float* wsf   = (float*)d_ws;
  float* zn    = wsf + ZN_OFF;
  float* ACC   = wsf + ACC_OFF;
  float* stats = wsf + STATS_OFF;
  float* cqs   = wsf + CQ_OFF;
  float* iks   = wsf + IK_OFF;
  unsigned short* u16b = (unsigned short*)(wsf + U16_OFF);
  unsigned short* WT   = u16b + WT_U16;
  unsigned short* qkvb = u16b + QKVB_U16;
  unsigned short* VT   = u16b + VT_U16;

  unsigned short* Qb = qkvb;
  unsigned short* Kb = qkvb + (size_t)H * SEQ * HD;
  float* q2s = stats;
  float* k2s = stats + (size_t)H * SEQ;
  const unsigned short* qprobe = (const unsigned short*)Xq;

  double lb1 = lgamma(EDIM / 2.0) + lgamma(0.5) - lgamma(EDIM / 2.0 + 0.5);
  double lb2 = lgamma(HD / 2.0)   + lgamma(0.5) - lgamma(HD / 2.0 + 0.5);
  float beta_scale = (float)exp(lb1 - lb2);

  hipMemsetAsync(zn, 0, (size_t)(3 * EDIM + H * SEQ * 80) * sizeof(float), stream);
  wcvt_kernel<<<dim3(64, 3), dim3(256), 0, stream>>>(Wq, Wk, Wv, qprobe, WT, zn);
  hlinear_kernel<<<dim3(SEQ / 16, 3), dim3(256), 0, stream>>>(
      Xq, Xk, Xv, WT, Bq, Bk, Bv, zn, qkvb, stats, cqs, iks, VT);
  attn_kernel<<<dim3(32 * 8, H), dim3(256), 0, stream>>>(
      Qb, Kb, VT, q2s, k2s, cqs, iks, tau, gam, qprobe, ACC);
  attn_fin_kernel<<<dim3(128, H), dim3(64), 0, stream>>>(
      ACC, (float*)d_out, beta_scale);
}